// Round 4
// baseline (516.627 us; speedup 1.0000x reference)
//
#include <hip/hip_runtime.h>
#include <hip/hip_bf16.h>

// HopfieldLayer: out = softmax(x @ Wl^T * beta) @ Wc^T
//   x [16384,768] f32, Wl [4096,768] f32, Wc [768,4096] f32 -> out [16384,768] f32
// R4: producer-consumer wave specialization. 8 waves/block: 4 compute (64x64
// each, 2x2), 4 producers each owning one ring stage (BK=32, 4x16KB LDS ring).
// NO __syncthreads in the K-loop: LDS flag handshake; only producer waves ever
// wait on vmcnt, so compute waves never see the barrier drain that capped the
// 2-barrier structure at MfmaUtil ~20%.

#define NTOK   16384
#define DIM    768
#define NPROT  4096
#define BETA_F 0.03608439182428583f

typedef __bf16 bf16_t;
typedef __bf16 bf16x8 __attribute__((ext_vector_type(8)));
typedef float  floatx4 __attribute__((ext_vector_type(4)));

// ---------------------------------------------------------------- async 16B copy
__device__ __forceinline__ void async_copy16(const bf16_t* g, void* l) {
  __builtin_amdgcn_global_load_lds(
      (__attribute__((address_space(1))) const void*)g,
      (__attribute__((address_space(3))) void*)l, 16, 0, 0);
}

// ---------------------------------------------------------------- f32 -> bf16 (all 3 inputs)
__global__ __launch_bounds__(256) void cvt_all(
    const float* __restrict__ x, const float* __restrict__ wl,
    const float* __restrict__ wc, bf16_t* __restrict__ xb,
    bf16_t* __restrict__ wlb, bf16_t* __restrict__ wcb,
    int nx8, int nw8, int nc8) {
  int i = blockIdx.x * 256 + threadIdx.x;
  const float* in; bf16_t* out; int k;
  if (i < nx8)            { in = x;  out = xb;  k = i; }
  else if (i < nx8 + nw8) { in = wl; out = wlb; k = i - nx8; }
  else if (i < nx8 + nw8 + nc8) { in = wc; out = wcb; k = i - nx8 - nw8; }
  else return;
  const float4* in4 = (const float4*)in;
  float4 a = in4[2 * k], b = in4[2 * k + 1];
  bf16x8 o;
  o[0] = (bf16_t)a.x; o[1] = (bf16_t)a.y; o[2] = (bf16_t)a.z; o[3] = (bf16_t)a.w;
  o[4] = (bf16_t)b.x; o[5] = (bf16_t)b.y; o[6] = (bf16_t)b.z; o[7] = (bf16_t)b.w;
  ((bf16x8*)out)[k] = o;
}

// ---------------------------------------------------------------- gemm C = A * B^T
// A: M x K row-major bf16, B: N x K row-major bf16. 128x128 block tile.
// Ring: 4 stages x 16KB (A frags 8KB + B frags 8KB, fragment-ordered: frag f is
// 1KB, lane slot l holds row (f*16 + (l&15)), k ((l>>4)*8 ..+7) -- matches both
// global_load_lds uniform-base+lane*16 and conflict-free ds_read_b128).
// Handshake: prod_flag[s] = laps staged (single producer wave per stage, plain
// volatile store); cons_cnt[s] = consumer-wave completions (LDS atomicAdd).
// EPI 0: P = exp(beta*acc) bf16 + shuffle rowsum + atomicAdd.  EPI 1: acc/rowsum.
template <int EPI>
__global__ __launch_bounds__(512, 4)
void gemm_bt(const bf16_t* __restrict__ A, const bf16_t* __restrict__ B,
             void* __restrict__ Cv, float* __restrict__ rowsum,
             const int K, const int N) {
  __shared__ alignas(16) char lds[4 * 16384 + 32];
  volatile int* prod_flag = (volatile int*)(lds + 65536);       // [4]
  int*          cons_cnt  = (int*)(lds + 65536 + 16);           // [4]
  volatile int* cons_cntv = (volatile int*)cons_cnt;

  const int tid = threadIdx.x;
  const int l   = tid & 63;
  const int w   = tid >> 6;      // 0..7
  const int lr  = l & 15;
  const int lk  = (l >> 4) << 3;
  const int m0  = blockIdx.x * 128;
  const int n0  = blockIdx.y * 128;
  const int iters = K >> 5;      // 24 (GEMM1) / 128 (GEMM2); both % 4 == 0

  if (tid < 8) ((int*)(lds + 65536))[tid] = 0;
  __syncthreads();  // the only barrier in the kernel

  if (w >= 4) {
    // ---------------- producer wave: owns ring stage s, iterations s, s+4, ...
    const int s = w - 4;
    bf16x8* Af = (bf16x8*)(lds + s * 16384);
    bf16x8* Bf = (bf16x8*)(lds + s * 16384 + 8192);
    int ab[8], bb[8];
#pragma unroll
    for (int f = 0; f < 8; ++f) {
      ab[f] = (m0 + 16 * f + lr) * K + lk;
      bb[f] = (n0 + 16 * f + lr) * K + lk;
    }
    int L = 0;
    for (int it = s; it < iters; it += 4, ++L) {
      while (cons_cntv[s] < 4 * L) __builtin_amdgcn_s_sleep(1);
      asm volatile("" ::: "memory");   // loads must not hoist above the poll
      const int k0 = it << 5;
#pragma unroll
      for (int f = 0; f < 8; ++f) {
        async_copy16(A + ab[f] + k0, Af + f * 64);
        async_copy16(B + bb[f] + k0, Bf + f * 64);
      }
      asm volatile("s_waitcnt vmcnt(0)" ::: "memory");  // only THIS wave's loads
      if (l == 0) prod_flag[s] = L + 1;
    }
    return;  // producers exit; consumers do the epilogue
  }

  // ---------------- consumer wave: 64x64 tile at (wr, wc) of the 128x128 block
  const int wr = w >> 1;
  const int wc = w & 1;
  const floatx4 z = {0.f, 0.f, 0.f, 0.f};
  floatx4 acc[4][4];
#pragma unroll
  for (int mt = 0; mt < 4; ++mt)
#pragma unroll
    for (int nt = 0; nt < 4; ++nt) acc[mt][nt] = z;

  for (int it = 0; it < iters; ++it) {
    const int s = it & 3;
    const int want = (it >> 2) + 1;
    while (prod_flag[s] < want) __builtin_amdgcn_s_sleep(1);
    asm volatile("" ::: "memory");     // data reads must not hoist above poll
    const bf16x8* Af = (const bf16x8*)(lds + s * 16384);
    const bf16x8* Bf = (const bf16x8*)(lds + s * 16384 + 8192);
    bf16x8 af[4], bg[4];
#pragma unroll
    for (int mt = 0; mt < 4; ++mt) af[mt] = Af[(wr * 4 + mt) * 64 + l];
#pragma unroll
    for (int nt = 0; nt < 4; ++nt) bg[nt] = Bf[(wc * 4 + nt) * 64 + l];
#pragma unroll
    for (int mt = 0; mt < 4; ++mt)
#pragma unroll
      for (int nt = 0; nt < 4; ++nt)
        acc[mt][nt] = __builtin_amdgcn_mfma_f32_16x16x32_bf16(af[mt], bg[nt],
                                                              acc[mt][nt], 0, 0, 0);
    asm volatile("" ::: "memory");     // signal must not reorder above the reads
    if (l == 0) atomicAdd(&cons_cnt[s], 1);
  }

  // C/D layout (verified m89): col = lane&15, row = (lane>>4)*4 + i
  const int rowb = m0 + wr * 64;
  const int colb = n0 + wc * 64;
  if (EPI == 0) {
    bf16_t* P = (bf16_t*)Cv;
#pragma unroll
    for (int mt = 0; mt < 4; ++mt) {
      float rsum[4] = {0.f, 0.f, 0.f, 0.f};
#pragma unroll
      for (int nt = 0; nt < 4; ++nt) {
#pragma unroll
        for (int i = 0; i < 4; ++i) {
          const float e = __expf(acc[mt][nt][i] * BETA_F);
          const int row = rowb + mt * 16 + (l >> 4) * 4 + i;
          const int col = colb + nt * 16 + lr;
          P[row * N + col] = (bf16_t)e;
          rsum[i] += e;
        }
      }
#pragma unroll
      for (int i = 0; i < 4; ++i) {
        float s = rsum[i];
        s += __shfl_xor(s, 1);
        s += __shfl_xor(s, 2);
        s += __shfl_xor(s, 4);
        s += __shfl_xor(s, 8);
        if (lr == 0)
          atomicAdd(&rowsum[rowb + mt * 16 + (l >> 4) * 4 + i], s);
      }
    }
  } else {
    float* O = (float*)Cv;
#pragma unroll
    for (int mt = 0; mt < 4; ++mt) {
#pragma unroll
      for (int i = 0; i < 4; ++i) {
        const int row = rowb + mt * 16 + (l >> 4) * 4 + i;
        const float inv = 1.0f / rowsum[row];
#pragma unroll
        for (int nt = 0; nt < 4; ++nt)
          O[row * N + colb + nt * 16 + lr] = acc[mt][nt][i] * inv;
      }
    }
  }
}

// ---------------------------------------------------------------- fallback (no ws)
__global__ __launch_bounds__(256) void hopfield_fallback(
    const float* __restrict__ x, const float* __restrict__ wl,
    const float* __restrict__ wc, float* __restrict__ out) {
  __shared__ float  xs[8 * 768];
  __shared__ bf16_t ps[8 * 4096];
  __shared__ float  rs[8];
  const int tid = threadIdx.x;
  const int r0  = blockIdx.x * 8;
  if (tid < 8) rs[tid] = 0.f;
  for (int i = tid; i < 8 * 768; i += 256)
    xs[i] = x[(r0 + (i / 768)) * 768 + (i % 768)];
  __syncthreads();

  float lsum[8] = {0, 0, 0, 0, 0, 0, 0, 0};
  for (int p = tid; p < 4096; p += 256) {
    float s[8] = {0, 0, 0, 0, 0, 0, 0, 0};
    for (int d = 0; d < 768; ++d) {
      const float wv = wl[p * 768 + d];
#pragma unroll
      for (int r = 0; r < 8; ++r) s[r] += xs[r * 768 + d] * wv;
    }
#pragma unroll
    for (int r = 0; r < 8; ++r) {
      const float e = __expf(s[r] * BETA_F);
      ps[r * 4096 + p] = (bf16_t)e;
      lsum[r] += e;
    }
  }
#pragma unroll
  for (int r = 0; r < 8; ++r) atomicAdd(&rs[r], lsum[r]);
  __syncthreads();

  for (int d = tid; d < 768; d += 256) {
    float o[8] = {0, 0, 0, 0, 0, 0, 0, 0};
    for (int p = 0; p < 4096; ++p) {
      const float wv = wc[d * 4096 + p];
#pragma unroll
      for (int r = 0; r < 8; ++r) o[r] += (float)ps[r * 4096 + p] * wv;
    }
#pragma unroll
    for (int r = 0; r < 8; ++r) out[(r0 + r) * 768 + d] = o[r] / rs[r];
  }
}

// ---------------------------------------------------------------- launcher
extern "C" void kernel_launch(void* const* d_in, const int* in_sizes, int n_in,
                              void* d_out, int out_size, void* d_ws, size_t ws_size,
                              hipStream_t stream) {
  (void)in_sizes; (void)n_in; (void)out_size;
  const float* x  = (const float*)d_in[0];
  const float* wl = (const float*)d_in[1];
  const float* wc = (const float*)d_in[2];
  float* out = (float*)d_out;

  const size_t xb_e = (size_t)NTOK * DIM;
  const size_t wl_e = (size_t)NPROT * DIM;
  const size_t wc_e = (size_t)DIM * NPROT;
  const size_t P_e  = (size_t)NTOK * NPROT;
  const size_t need = (xb_e + wl_e + wc_e + P_e) * 2 + (size_t)NTOK * 4;

  if (ws_size >= need) {
    char* ws = (char*)d_ws;
    bf16_t* xb  = (bf16_t*)ws;  ws += xb_e * 2;
    bf16_t* wlb = (bf16_t*)ws;  ws += wl_e * 2;
    bf16_t* wcb = (bf16_t*)ws;  ws += wc_e * 2;
    bf16_t* P   = (bf16_t*)ws;  ws += P_e * 2;
    float* rowsum = (float*)ws;

    hipMemsetAsync(rowsum, 0, NTOK * sizeof(float), stream);
    const int nx8 = (int)(xb_e / 8), nw8 = (int)(wl_e / 8), nc8 = (int)(wc_e / 8);
    cvt_all<<<(nx8 + nw8 + nc8 + 255) / 256, 256, 0, stream>>>(
        x, wl, wc, xb, wlb, wcb, nx8, nw8, nc8);
    // scores+exp+rowsum: M=16384, N=4096, K=768
    gemm_bt<0><<<dim3(NTOK / 128, NPROT / 128), 512, 0, stream>>>(
        xb, wlb, (void*)P, rowsum, DIM, NPROT);
    // content+normalize: M=16384, N=768, K=4096
    gemm_bt<1><<<dim3(NTOK / 128, DIM / 128), 512, 0, stream>>>(
        P, wcb, (void*)out, rowsum, NPROT, DIM);
  } else {
    hopfield_fallback<<<NTOK / 8, 256, 0, stream>>>(x, wl, wc, out);
  }
}